// Round 12
// baseline (1578.204 us; speedup 1.0000x reference)
//
#include <hip/hip_runtime.h>
#include <hip/hip_bf16.h>
#include <stdint.h>

// GRU sequence decoder, fused. B=32768, H=L=512, VOCAB=10, SEQ=6.
// R12 = R10 (573us best) with ONE change: wave partition wn8 -> wm2 x wn4.
// Wave owns 2 btiles (32 rows) x 8 jtiles. Per kk: 2 hf ds_reads feed 12 MFMA
// (was 4:12), 6 wf loads feed 12 MFMA (was 12:12). Per-wave per step:
// ds_read_b128 256->128, global loads 768->384, VALU addr ~halved. LDS port
// 2MB -> 1MB per block-step (was the largest cost term: ~24K cyc/CU @85B/cyc
// vs MFMA 7.4K/SIMD). Weight bytes per block unchanged (each chunk read by 2
// waves, L2 absorbs). acc 48 + gpre 24 unchanged -> no new spill risk.
// R11 lessons: arch-VGPR cap stays ~128 when AGPRs in use (gireg spilled);
// SQ_LDS_BANK_CONFLICT here is the inherent b128 multi-phase cost, not
// actionable — the lever is FEWER LDS instructions, not layout.
// Kept from R10: h double-buffered in LDS (one barrier/step), XOR swizzle
// byte^=(row&7)<<4, gi in ws per-lane frag order with pass-head prefetch,
// weights pre-packed frag-order (L2-resident), logits on waves 0-3.

typedef __bf16 bf16_t;
typedef bf16_t bf16x8 __attribute__((ext_vector_type(8)));
typedef bf16_t bf16x4 __attribute__((ext_vector_type(4)));
typedef float  f32x4  __attribute__((ext_vector_type(4)));
typedef float  f32x2  __attribute__((ext_vector_type(2)));

#define THREADS 512
#define BM      64
#define NBLK    512
#define NSTEP   6

// ws layout (bytes)
#define WIH_OFF 0u            // 96 nt * 16 kk * 64 lane * 16B = 1572864
#define WHH_OFF 1572864u
#define WOP_OFF 3145728u      // 16 kk * 64 lane * 16B = 16384
#define GI_OFF  4194304u      // 512 blk * 24576 chunks * 8B = 100663296

static __device__ __forceinline__ float sigm(float v) { return 1.0f / (1.0f + __expf(-v)); }
static __device__ __forceinline__ float tanhf_(float v) {
  v = fminf(fmaxf(v, -12.0f), 12.0f);
  float e = __expf(2.0f * v);
  return 1.0f - 2.0f / (e + 1.0f);
}
static __device__ __forceinline__ f32x4 up4(bf16x4 v) {
  f32x4 o; o[0] = (float)v[0]; o[1] = (float)v[1]; o[2] = (float)v[2]; o[3] = (float)v[3];
  return o;
}
static __device__ __forceinline__ bf16x4 pk4(f32x4 v) {
  bf16x4 o; o[0] = (bf16_t)v[0]; o[1] = (bf16_t)v[1]; o[2] = (bf16_t)v[2]; o[3] = (bf16_t)v[3];
  return o;
}

// Pack weights into MFMA A-frag order:
//   chunk[(nt*16 + kk)*64 + lane] = w[nt*16 + (lane&15)][kk*32 + (lane>>4)*8 .. +8]
__global__ void prep_kernel(const float* __restrict__ wih_f, const float* __restrict__ whh_f,
                            const float* __restrict__ wout_f,
                            bf16x8* __restrict__ wihPk, bf16x8* __restrict__ whhPk,
                            bf16x8* __restrict__ wopPk) {
  int c = blockIdx.x * 256 + threadIdx.x;
  int lane = c & 63, l15 = lane & 15, lk = (lane >> 4) & 3;
  if (c < 196608) {
    int cid = (c < 98304) ? c : c - 98304;
    const float* src = (c < 98304) ? wih_f : whh_f;
    bf16x8* dst = (c < 98304) ? wihPk : whhPk;
    int kk = (cid >> 6) & 15;
    int nt = cid >> 10;
    const float* p = src + (size_t)(nt * 16 + l15) * 512 + kk * 32 + lk * 8;
    bf16x8 o;
    #pragma unroll
    for (int i = 0; i < 8; ++i) o[i] = (bf16_t)p[i];
    dst[cid] = o;
  } else if (c < 197632) {
    int cid = c - 196608;          // vocab tile: 16 kk * 64 lane
    int kk = cid >> 6;
    bf16x8 o;
    if (l15 < 10) {
      const float* p = wout_f + (size_t)l15 * 512 + kk * 32 + lk * 8;
      #pragma unroll
      for (int i = 0; i < 8; ++i) o[i] = (bf16_t)p[i];
    } else {
      #pragma unroll
      for (int i = 0; i < 8; ++i) o[i] = (bf16_t)0.0f;
    }
    wopPk[cid] = o;
  }
}

__global__ __launch_bounds__(THREADS, 1) void gru_kernel(
    const float* __restrict__ x, const float* __restrict__ b_ih,
    const float* __restrict__ b_hh, const float* __restrict__ b_out,
    const bf16x8* __restrict__ wih, const bf16x8* __restrict__ whh,
    const bf16x8* __restrict__ wop,
    bf16x4* __restrict__ gi, float* __restrict__ out) {
  // Two h tiles: 64 rows x 512 bf16 each (row = 1024B); logical col-byte L of
  // row r stored at physical L ^ ((r&7)<<4). Step t reads cur, writes nxt,
  // one barrier, swap.
  __shared__ __align__(16) char hlds[2 * BM * 1024];

  const int tid   = (int)threadIdx.x;
  const int lane  = tid & 63;
  const int wq    = tid >> 6;      // 0..7
  const int wm    = wq >> 2;       // batch half: btiles {wm*2, wm*2+1}
  const int wn    = wq & 3;        // j quarter: jtiles [wn*8, wn*8+8)
  const int l15   = lane & 15;
  const int lk    = lane >> 4;
  const int brow0 = (int)blockIdx.x * BM;
  const int swz   = (l15 & 7) << 4;
  const int kbase = (lk * 16) ^ swz;        // b128 read col base (XOR with kk*64)
  const int cbase = (lk * 8) ^ swz;         // b64 cell col base (XOR with jt*32)

  char* cur = hlds;             // h_t
  char* nxt = hlds + BM * 1024; // h_{t+1}

  // ---------------- phase 0: x -> bf16 -> cur (h0 = x) ----------------
  #pragma unroll
  for (int it = 0; it < 16; ++it) {
    int f4  = it * THREADS + tid;
    int row = f4 >> 7, c4 = f4 & 127;
    float4 v = ((const float4*)(x + (size_t)(brow0 + row) * 512))[c4];
    bf16x4 h4 = { (bf16_t)v.x, (bf16_t)v.y, (bf16_t)v.z, (bf16_t)v.w };
    *(bf16x4*)(&cur[row * 1024 + ((c4 * 8) ^ ((row & 7) << 4))]) = h4;
  }
  __syncthreads();

  const size_t gibase = (size_t)blockIdx.x * 24576;  // bf16x4 chunks per block
  // gi chunk: ((jt*3 + g)*4 + bt)*64 + lane  (bt = global btile 0..3)

  // ---------------- gi phase: gi = x @ w_ih^T + biases ----------------
  #pragma unroll
  for (int p = 0; p < 4; ++p) {
    const int jt0 = wn * 8 + p * 2;
    f32x4 acc[2][3][2];
    #pragma unroll
    for (int jj = 0; jj < 2; ++jj)
      #pragma unroll
      for (int g = 0; g < 3; ++g)
        #pragma unroll
        for (int bl = 0; bl < 2; ++bl) acc[jj][g][bl] = (f32x4){0.f, 0.f, 0.f, 0.f};

    #pragma unroll 4
    for (int kk = 0; kk < 16; ++kk) {
      bf16x8 hf[2];
      #pragma unroll
      for (int bl = 0; bl < 2; ++bl)
        hf[bl] = *(const bf16x8*)(&cur[((wm * 2 + bl) * 16 + l15) * 1024 + ((kk * 64) ^ kbase)]);
      #pragma unroll
      for (int jj = 0; jj < 2; ++jj)
        #pragma unroll
        for (int g = 0; g < 3; ++g) {
          bf16x8 wf = wih[((g * 32 + jt0 + jj) * 16 + kk) * 64 + lane];
          #pragma unroll
          for (int bl = 0; bl < 2; ++bl)
            acc[jj][g][bl] = __builtin_amdgcn_mfma_f32_16x16x32_bf16(wf, hf[bl], acc[jj][g][bl], 0, 0, 0);
        }
    }
    #pragma unroll
    for (int jj = 0; jj < 2; ++jj) {
      const int jt = jt0 + jj;
      int j = jt * 16 + lk * 4;
      f32x4 b0 = *(const f32x4*)(b_ih + j) + *(const f32x4*)(b_hh + j);
      f32x4 b1 = *(const f32x4*)(b_ih + 512 + j) + *(const f32x4*)(b_hh + 512 + j);
      f32x4 b2 = *(const f32x4*)(b_ih + 1024 + j);   // b_hh_n stays separate (x r)
      #pragma unroll
      for (int bl = 0; bl < 2; ++bl) {
        int bt = wm * 2 + bl;
        gi[gibase + ((size_t)((jt * 3 + 0) * 4 + bt) << 6) + lane] = pk4(acc[jj][0][bl] + b0);
        gi[gibase + ((size_t)((jt * 3 + 1) * 4 + bt) << 6) + lane] = pk4(acc[jj][1][bl] + b1);
        gi[gibase + ((size_t)((jt * 3 + 2) * 4 + bt) << 6) + lane] = pk4(acc[jj][2][bl] + b2);
      }
    }
  }
  // (no barrier: cur unchanged; gi is same-lane RAW, HW-ordered)

  // ---------------- 6 recurrent steps (one barrier each) ----------------
  for (int t = 0; t < NSTEP; ++t) {
    #pragma unroll
    for (int p = 0; p < 4; ++p) {
      const int jt0 = wn * 8 + p * 2;

      // prefetch this pass's 12 gi chunks (latency hides under the k-loop)
      bf16x4 gpre[2][3][2];
      #pragma unroll
      for (int jj = 0; jj < 2; ++jj)
        #pragma unroll
        for (int g = 0; g < 3; ++g)
          #pragma unroll
          for (int bl = 0; bl < 2; ++bl)
            gpre[jj][g][bl] = gi[gibase +
                ((size_t)(((jt0 + jj) * 3 + g) * 4 + wm * 2 + bl) << 6) + lane];

      f32x4 acc[2][3][2];
      #pragma unroll
      for (int jj = 0; jj < 2; ++jj)
        #pragma unroll
        for (int g = 0; g < 3; ++g)
          #pragma unroll
          for (int bl = 0; bl < 2; ++bl) acc[jj][g][bl] = (f32x4){0.f, 0.f, 0.f, 0.f};

      #pragma unroll 4
      for (int kk = 0; kk < 16; ++kk) {
        bf16x8 hf[2];
        #pragma unroll
        for (int bl = 0; bl < 2; ++bl)
          hf[bl] = *(const bf16x8*)(&cur[((wm * 2 + bl) * 16 + l15) * 1024 + ((kk * 64) ^ kbase)]);
        #pragma unroll
        for (int jj = 0; jj < 2; ++jj)
          #pragma unroll
          for (int g = 0; g < 3; ++g) {
            bf16x8 wf = whh[((g * 32 + jt0 + jj) * 16 + kk) * 64 + lane];
            #pragma unroll
            for (int bl = 0; bl < 2; ++bl)
              acc[jj][g][bl] = __builtin_amdgcn_mfma_f32_16x16x32_bf16(wf, hf[bl], acc[jj][g][bl], 0, 0, 0);
          }
      }
      // GRU cell epilogue: gi from regs; h_old from LDS; h_new -> nxt.
      #pragma unroll
      for (int jj = 0; jj < 2; ++jj) {
        const int jt = jt0 + jj;
        int j = jt * 16 + lk * 4;
        f32x4 bn4 = *(const f32x4*)(b_hh + 1024 + j);
        #pragma unroll
        for (int bl = 0; bl < 2; ++bl) {
          int row = (wm * 2 + bl) * 16 + l15;
          f32x4 gr  = up4(gpre[jj][0][bl]);
          f32x4 gz  = up4(gpre[jj][1][bl]);
          f32x4 gn  = up4(gpre[jj][2][bl]);
          f32x4 hov = up4(*(const bf16x4*)(&cur[row * 1024 + ((jt * 32) ^ cbase)]));
          f32x4 hv;
          #pragma unroll
          for (int r = 0; r < 4; ++r) {
            float rv = sigm(gr[r] + acc[jj][0][bl][r]);
            float zv = sigm(gz[r] + acc[jj][1][bl][r]);
            float nv = tanhf_(gn[r] + rv * (acc[jj][2][bl][r] + bn4[r]));
            hv[r] = (1.0f - zv) * nv + zv * hov[r];
          }
          *(bf16x4*)(&nxt[row * 1024 + ((jt * 32) ^ cbase)]) = pk4(hv);
        }
      }
    }
    __syncthreads();   // h_{t+1} writes drained & visible; h_t reads all done

    { char* tmp = cur; cur = nxt; nxt = tmp; }   // cur = h_{t+1}

    // logits_t = h_{t+1} @ w_out^T + b_out ; waves 0..3 each own one btile.
    // Concurrent with other waves' next-step k-loop (both only read cur;
    // epilogue writes go to nxt — disjoint).
    if (wq < 4) {
      f32x4 lacc = (f32x4){0.f, 0.f, 0.f, 0.f};
      #pragma unroll 4
      for (int kk = 0; kk < 16; ++kk) {
        bf16x8 hf = *(const bf16x8*)(&cur[(wq * 16 + l15) * 1024 + ((kk * 64) ^ kbase)]);
        bf16x8 wf = wop[kk * 64 + lane];
        lacc = __builtin_amdgcn_mfma_f32_16x16x32_bf16(wf, hf, lacc, 0, 0, 0);
      }
      size_t ob = (size_t)(brow0 + wq * 16 + l15) * 60 + t * 10 + lk * 4;
      if (lk < 2) {
        f32x2 a = { lacc[0] + b_out[lk * 4 + 0], lacc[1] + b_out[lk * 4 + 1] };
        f32x2 b = { lacc[2] + b_out[lk * 4 + 2], lacc[3] + b_out[lk * 4 + 3] };
        *(f32x2*)(out + ob) = a;
        *(f32x2*)(out + ob + 2) = b;
      } else if (lk == 2) {
        f32x2 a = { lacc[0] + b_out[8], lacc[1] + b_out[9] };
        *(f32x2*)(out + ob) = a;
      }
    }
  }
}

extern "C" void kernel_launch(void* const* d_in, const int* in_sizes, int n_in,
                              void* d_out, int out_size, void* d_ws, size_t ws_size,
                              hipStream_t stream) {
  const float* x     = (const float*)d_in[0];
  const float* wih_f = (const float*)d_in[1];
  const float* whh_f = (const float*)d_in[2];
  const float* b_ih  = (const float*)d_in[3];
  const float* b_hh  = (const float*)d_in[4];
  const float* wout  = (const float*)d_in[5];
  const float* b_out = (const float*)d_in[6];

  char* ws = (char*)d_ws;
  bf16x8* wihPk = (bf16x8*)(ws + WIH_OFF);
  bf16x8* whhPk = (bf16x8*)(ws + WHH_OFF);
  bf16x8* wopPk = (bf16x8*)(ws + WOP_OFF);
  bf16x4* gi    = (bf16x4*)(ws + GI_OFF);

  prep_kernel<<<772, 256, 0, stream>>>(wih_f, whh_f, wout, wihPk, whhPk, wopPk);
  gru_kernel<<<NBLK, THREADS, 0, stream>>>(x, b_ih, b_hh, b_out,
                                           wihPk, whhPk, wopPk, gi, (float*)d_out);
}

// Round 13
// 813.651 us; speedup vs baseline: 1.9397x; 1.9397x over previous
//
#include <hip/hip_runtime.h>
#include <hip/hip_bf16.h>
#include <stdint.h>

// GRU sequence decoder, fused. B=32768, H=L=512, VOCAB=10, SEQ=6.
// R13: BM=128 to halve the whh L2 stream (156us -> 78us aggregate), the
// largest non-MFMA term in R10's 573us. Register model (R2/R11/R12 evidence):
// per-wave budget 256 unified; acc in AGPR is cheap (R2: 96 AGPR + 120 arch,
// no spill); arch VGPR must stay <= ~128. So: acc[3][8]=96 AGPR, gpre r/z
// only (32 arch), gn loaded in epilogue, kk unroll 2, 3 wf loads/kk (R12's
// 6 wf/kk x unroll4 was the spill trigger).
//  - 8 waves, wave owns jtiles [wq*4,wq*4+4) x ALL 8 btiles (128 rows).
//  - h single-buffered in LDS (128KB, XOR swizzle); h_new via hst global
//    round-trip (R6-proven), 2 barriers/step.
//  - gi in ws per-lane frag order (same-lane RAW); weights pre-packed
//    frag-order, L2/L3-resident; logits: all 8 waves, wave wq owns btile wq.
//  - __launch_bounds__(512,1); 1 block/CU by design (R7/R8: 2nd block never
//    co-resides). NBLK=256.

typedef __bf16 bf16_t;
typedef bf16_t bf16x8 __attribute__((ext_vector_type(8)));
typedef bf16_t bf16x4 __attribute__((ext_vector_type(4)));
typedef float  f32x4  __attribute__((ext_vector_type(4)));
typedef float  f32x2  __attribute__((ext_vector_type(2)));

#define THREADS 512
#define BM      128
#define NBLK    256
#define NSTEP   6

// ws layout (bytes)
#define WIH_OFF 0u            // 96 nt * 16 kk * 64 lane * 16B = 1572864
#define WHH_OFF 1572864u
#define WOP_OFF 3145728u      // 16 kk * 64 lane * 16B = 16384
#define GI_OFF  4194304u      // 256 blk * 49152 chunks * 8B = 100663296
#define HST_OFF 104857600u    // 256 blk * 256 chunks * 512B = 33554432

static __device__ __forceinline__ float sigm(float v) { return 1.0f / (1.0f + __expf(-v)); }
static __device__ __forceinline__ float tanhf_(float v) {
  v = fminf(fmaxf(v, -12.0f), 12.0f);
  float e = __expf(2.0f * v);
  return 1.0f - 2.0f / (e + 1.0f);
}
static __device__ __forceinline__ f32x4 up4(bf16x4 v) {
  f32x4 o; o[0] = (float)v[0]; o[1] = (float)v[1]; o[2] = (float)v[2]; o[3] = (float)v[3];
  return o;
}
static __device__ __forceinline__ bf16x4 pk4(f32x4 v) {
  bf16x4 o; o[0] = (bf16_t)v[0]; o[1] = (bf16_t)v[1]; o[2] = (bf16_t)v[2]; o[3] = (bf16_t)v[3];
  return o;
}

// Pack weights into MFMA A-frag order (unchanged from R10):
//   chunk[(nt*16 + kk)*64 + lane] = w[nt*16 + (lane&15)][kk*32 + (lane>>4)*8 .. +8]
__global__ void prep_kernel(const float* __restrict__ wih_f, const float* __restrict__ whh_f,
                            const float* __restrict__ wout_f,
                            bf16x8* __restrict__ wihPk, bf16x8* __restrict__ whhPk,
                            bf16x8* __restrict__ wopPk) {
  int c = blockIdx.x * 256 + threadIdx.x;
  int lane = c & 63, l15 = lane & 15, lk = (lane >> 4) & 3;
  if (c < 196608) {
    int cid = (c < 98304) ? c : c - 98304;
    const float* src = (c < 98304) ? wih_f : whh_f;
    bf16x8* dst = (c < 98304) ? wihPk : whhPk;
    int kk = (cid >> 6) & 15;
    int nt = cid >> 10;
    const float* p = src + (size_t)(nt * 16 + l15) * 512 + kk * 32 + lk * 8;
    bf16x8 o;
    #pragma unroll
    for (int i = 0; i < 8; ++i) o[i] = (bf16_t)p[i];
    dst[cid] = o;
  } else if (c < 197632) {
    int cid = c - 196608;          // vocab tile: 16 kk * 64 lane
    int kk = cid >> 6;
    bf16x8 o;
    if (l15 < 10) {
      const float* p = wout_f + (size_t)l15 * 512 + kk * 32 + lk * 8;
      #pragma unroll
      for (int i = 0; i < 8; ++i) o[i] = (bf16_t)p[i];
    } else {
      #pragma unroll
      for (int i = 0; i < 8; ++i) o[i] = (bf16_t)0.0f;
    }
    wopPk[cid] = o;
  }
}

__global__ __launch_bounds__(THREADS, 1) void gru_kernel(
    const float* __restrict__ x, const float* __restrict__ b_ih,
    const float* __restrict__ b_hh, const float* __restrict__ b_out,
    const bf16x8* __restrict__ wih, const bf16x8* __restrict__ whh,
    const bf16x8* __restrict__ wop,
    bf16x4* __restrict__ gi, bf16x4* __restrict__ hst, float* __restrict__ out) {
  // h tile: 128 rows x 512 bf16 (row = 1024B); logical col-byte L of row r at
  // physical L ^ ((r&7)<<4). Single buffer; h_new staged via hst (global).
  __shared__ __align__(16) char hlds[BM * 1024];

  const int tid   = (int)threadIdx.x;
  const int lane  = tid & 63;
  const int wq    = tid >> 6;      // 0..7: wave owns jtiles [wq*4, wq*4+4)
  const int l15   = lane & 15;
  const int lk    = lane >> 4;
  const int brow0 = (int)blockIdx.x * BM;
  const int swz   = (l15 & 7) << 4;
  const int kbase = (lk * 16) ^ swz;        // b128 read col base (XOR with kk*64)
  const int cbase = (lk * 8) ^ swz;         // b64 cell col base (XOR with jt*32)

  // ---------------- phase 0: x -> bf16 -> hlds (h0 = x) ----------------
  #pragma unroll
  for (int it = 0; it < 32; ++it) {
    int f4  = it * THREADS + tid;
    int row = f4 >> 7, c4 = f4 & 127;
    float4 v = ((const float4*)(x + (size_t)(brow0 + row) * 512))[c4];
    bf16x4 h4 = { (bf16_t)v.x, (bf16_t)v.y, (bf16_t)v.z, (bf16_t)v.w };
    *(bf16x4*)(&hlds[row * 1024 + ((c4 * 8) ^ ((row & 7) << 4))]) = h4;
  }
  __syncthreads();

  const size_t gibase = (size_t)blockIdx.x * 49152;  // bf16x4 chunks per block
  // gi chunk: ((jt*3 + g)*8 + bt)*64 + lane,  jt = wq*4 + p, bt 0..7
  const size_t hstbase = (size_t)blockIdx.x * 16384; // 256 chunks * 64
  // hst chunk: (jt*8 + bt)*64 + lane

  // ---------------- gi phase: gi = x @ w_ih^T + biases ----------------
  #pragma unroll
  for (int p = 0; p < 4; ++p) {
    const int jt = wq * 4 + p;
    f32x4 acc[3][8];
    #pragma unroll
    for (int g = 0; g < 3; ++g)
      #pragma unroll
      for (int bt = 0; bt < 8; ++bt) acc[g][bt] = (f32x4){0.f, 0.f, 0.f, 0.f};

    #pragma unroll 2
    for (int kk = 0; kk < 16; ++kk) {
      bf16x8 hf[8];
      #pragma unroll
      for (int bt = 0; bt < 8; ++bt)
        hf[bt] = *(const bf16x8*)(&hlds[(bt * 16 + l15) * 1024 + ((kk * 64) ^ kbase)]);
      #pragma unroll
      for (int g = 0; g < 3; ++g) {
        bf16x8 wf = wih[((g * 32 + jt) * 16 + kk) * 64 + lane];
        #pragma unroll
        for (int bt = 0; bt < 8; ++bt)
          acc[g][bt] = __builtin_amdgcn_mfma_f32_16x16x32_bf16(wf, hf[bt], acc[g][bt], 0, 0, 0);
      }
    }
    {
      int j = jt * 16 + lk * 4;
      f32x4 b0 = *(const f32x4*)(b_ih + j) + *(const f32x4*)(b_hh + j);
      f32x4 b1 = *(const f32x4*)(b_ih + 512 + j) + *(const f32x4*)(b_hh + 512 + j);
      f32x4 b2 = *(const f32x4*)(b_ih + 1024 + j);   // b_hh_n stays separate (x r)
      #pragma unroll
      for (int bt = 0; bt < 8; ++bt) {
        int cb = (jt * 3) * 8 + bt;
        gi[gibase + ((size_t)(cb + 0) << 6) + lane]  = pk4(acc[0][bt] + b0);
        gi[gibase + ((size_t)(cb + 8) << 6) + lane]  = pk4(acc[1][bt] + b1);
        gi[gibase + ((size_t)(cb + 16) << 6) + lane] = pk4(acc[2][bt] + b2);
      }
    }
  }
  // (no barrier: hlds unchanged; gi is same-lane RAW, HW-ordered)

  // ---------------- 6 recurrent steps (2 barriers each) ----------------
  for (int t = 0; t < NSTEP; ++t) {
    #pragma unroll
    for (int p = 0; p < 4; ++p) {
      const int jt = wq * 4 + p;
      const int cb = (jt * 3) * 8;

      // prefetch r,z gi chunks (32 arch VGPR); gn loaded in epilogue
      bf16x4 gpre[2][8];
      #pragma unroll
      for (int g = 0; g < 2; ++g)
        #pragma unroll
        for (int bt = 0; bt < 8; ++bt)
          gpre[g][bt] = gi[gibase + ((size_t)(cb + g * 8 + bt) << 6) + lane];

      f32x4 acc[3][8];
      #pragma unroll
      for (int g = 0; g < 3; ++g)
        #pragma unroll
        for (int bt = 0; bt < 8; ++bt) acc[g][bt] = (f32x4){0.f, 0.f, 0.f, 0.f};

      #pragma unroll 2
      for (int kk = 0; kk < 16; ++kk) {
        bf16x8 hf[8];
        #pragma unroll
        for (int bt = 0; bt < 8; ++bt)
          hf[bt] = *(const bf16x8*)(&hlds[(bt * 16 + l15) * 1024 + ((kk * 64) ^ kbase)]);
        #pragma unroll
        for (int g = 0; g < 3; ++g) {
          bf16x8 wf = whh[((g * 32 + jt) * 16 + kk) * 64 + lane];
          #pragma unroll
          for (int bt = 0; bt < 8; ++bt)
            acc[g][bt] = __builtin_amdgcn_mfma_f32_16x16x32_bf16(wf, hf[bt], acc[g][bt], 0, 0, 0);
        }
      }
      // GRU cell epilogue: h_new streamed to hst (coalesced; no reg hold)
      {
        int j = jt * 16 + lk * 4;
        f32x4 bn4 = *(const f32x4*)(b_hh + 1024 + j);
        bf16x4 gnp[8];
        #pragma unroll
        for (int bt = 0; bt < 8; ++bt)
          gnp[bt] = gi[gibase + ((size_t)(cb + 16 + bt) << 6) + lane];
        #pragma unroll
        for (int bt = 0; bt < 8; ++bt) {
          f32x4 gr  = up4(gpre[0][bt]);
          f32x4 gz  = up4(gpre[1][bt]);
          f32x4 gn  = up4(gnp[bt]);
          f32x4 hov = up4(*(const bf16x4*)(&hlds[(bt * 16 + l15) * 1024 +
                                                 ((jt * 32) ^ cbase)]));
          f32x4 hv;
          #pragma unroll
          for (int r = 0; r < 4; ++r) {
            float rv = sigm(gr[r] + acc[0][bt][r]);
            float zv = sigm(gz[r] + acc[1][bt][r]);
            float nv = tanhf_(gn[r] + rv * (acc[2][bt][r] + bn4[r]));
            hv[r] = (1.0f - zv) * nv + zv * hov[r];
          }
          hst[hstbase + ((size_t)((jt << 3) + bt) << 6) + lane] = pk4(hv);
        }
      }
    }
    __syncthreads();   // all h_t reads done; hst stores drained (vmcnt)

    // copy-back: reload own chunks from hst (L2-hit, coalesced), ds_write hlds
    #pragma unroll
    for (int p = 0; p < 4; ++p) {
      const int jt = wq * 4 + p;
      #pragma unroll
      for (int bt = 0; bt < 8; ++bt) {
        bf16x4 v = hst[hstbase + ((size_t)((jt << 3) + bt) << 6) + lane];
        *(bf16x4*)(&hlds[(bt * 16 + l15) * 1024 + ((jt * 32) ^ cbase)]) = v;
      }
    }
    __syncthreads();   // h_{t+1} visible

    // logits_t = h_{t+1} @ w_out^T + b_out ; wave wq owns btile wq (all 8)
    {
      f32x4 lacc = (f32x4){0.f, 0.f, 0.f, 0.f};
      #pragma unroll 2
      for (int kk = 0; kk < 16; ++kk) {
        bf16x8 hf = *(const bf16x8*)(&hlds[(wq * 16 + l15) * 1024 + ((kk * 64) ^ kbase)]);
        bf16x8 wf = wop[kk * 64 + lane];
        lacc = __builtin_amdgcn_mfma_f32_16x16x32_bf16(wf, hf, lacc, 0, 0, 0);
      }
      size_t ob = (size_t)(brow0 + wq * 16 + l15) * 60 + t * 10 + lk * 4;
      if (lk < 2) {
        f32x2 a = { lacc[0] + b_out[lk * 4 + 0], lacc[1] + b_out[lk * 4 + 1] };
        f32x2 b = { lacc[2] + b_out[lk * 4 + 2], lacc[3] + b_out[lk * 4 + 3] };
        *(f32x2*)(out + ob) = a;
        *(f32x2*)(out + ob + 2) = b;
      } else if (lk == 2) {
        f32x2 a = { lacc[0] + b_out[8], lacc[1] + b_out[9] };
        *(f32x2*)(out + ob) = a;
      }
    }
  }
}

extern "C" void kernel_launch(void* const* d_in, const int* in_sizes, int n_in,
                              void* d_out, int out_size, void* d_ws, size_t ws_size,
                              hipStream_t stream) {
  const float* x     = (const float*)d_in[0];
  const float* wih_f = (const float*)d_in[1];
  const float* whh_f = (const float*)d_in[2];
  const float* b_ih  = (const float*)d_in[3];
  const float* b_hh  = (const float*)d_in[4];
  const float* wout  = (const float*)d_in[5];
  const float* b_out = (const float*)d_in[6];

  char* ws = (char*)d_ws;
  bf16x8* wihPk = (bf16x8*)(ws + WIH_OFF);
  bf16x8* whhPk = (bf16x8*)(ws + WHH_OFF);
  bf16x8* wopPk = (bf16x8*)(ws + WOP_OFF);
  bf16x4* gi    = (bf16x4*)(ws + GI_OFF);
  bf16x4* hst   = (bf16x4*)(ws + HST_OFF);

  prep_kernel<<<772, 256, 0, stream>>>(wih_f, whh_f, wout, wihPk, whhPk, wopPk);
  gru_kernel<<<NBLK, THREADS, 0, stream>>>(x, b_ih, b_hh, b_out,
                                           wihPk, whhPk, wopPk, gi, hst, (float*)d_out);
}

// Round 14
// 650.545 us; speedup vs baseline: 2.4260x; 1.2507x over previous
//
#include <hip/hip_runtime.h>
#include <hip/hip_bf16.h>
#include <stdint.h>

// GRU sequence decoder, fused. B=32768, H=L=512, VOCAB=10, SEQ=6.
// R14 = R13 (BM=128: halves the per-MFMA L2 weight stream, 156->78us floor)
// with a strict register diet fixing R13's ~96MB spill:
//  - NO gpre/gnp register arrays: epilogue loads gi per-bt directly (R6-proven
//    spill-free pattern).
//  - kk-loop quad-split: wf[3] loaded once per kk, then two hf[4] quads of
//    12 MFMA each -> in-flight arch ~= 12*2(unroll) + 16 + addr ~ 60.
//  - acc[3][8] = 96 AGPR (R2-proven: 96 AGPR + ~120 arch = no spill).
// Structure: 8 waves, wave owns jtiles [wq*4,wq*4+4) x all 8 btiles (128 rows);
// h single-buffered in LDS (128KB, XOR swizzle byte^=(row&7)<<4); h_new via
// hst global round-trip (R6-proven), 2 barriers/step; gi in ws per-lane frag
// order (same-lane RAW); weights pre-packed frag order (L2-resident);
// logits: wave wq owns btile wq. __launch_bounds__(512,1), NBLK=256.

typedef __bf16 bf16_t;
typedef bf16_t bf16x8 __attribute__((ext_vector_type(8)));
typedef bf16_t bf16x4 __attribute__((ext_vector_type(4)));
typedef float  f32x4  __attribute__((ext_vector_type(4)));
typedef float  f32x2  __attribute__((ext_vector_type(2)));

#define THREADS 512
#define BM      128
#define NBLK    256
#define NSTEP   6

// ws layout (bytes)
#define WIH_OFF 0u            // 96 nt * 16 kk * 64 lane * 16B = 1572864
#define WHH_OFF 1572864u
#define WOP_OFF 3145728u      // 16 kk * 64 lane * 16B = 16384
#define GI_OFF  4194304u      // 256 blk * 49152 chunks * 8B = 100663296
#define HST_OFF 104857600u    // 256 blk * 256 chunks * 512B = 33554432

static __device__ __forceinline__ float sigm(float v) { return 1.0f / (1.0f + __expf(-v)); }
static __device__ __forceinline__ float tanhf_(float v) {
  v = fminf(fmaxf(v, -12.0f), 12.0f);
  float e = __expf(2.0f * v);
  return 1.0f - 2.0f / (e + 1.0f);
}
static __device__ __forceinline__ f32x4 up4(bf16x4 v) {
  f32x4 o; o[0] = (float)v[0]; o[1] = (float)v[1]; o[2] = (float)v[2]; o[3] = (float)v[3];
  return o;
}
static __device__ __forceinline__ bf16x4 pk4(f32x4 v) {
  bf16x4 o; o[0] = (bf16_t)v[0]; o[1] = (bf16_t)v[1]; o[2] = (bf16_t)v[2]; o[3] = (bf16_t)v[3];
  return o;
}

// Pack weights into MFMA A-frag order:
//   chunk[(nt*16 + kk)*64 + lane] = w[nt*16 + (lane&15)][kk*32 + (lane>>4)*8 .. +8]
__global__ void prep_kernel(const float* __restrict__ wih_f, const float* __restrict__ whh_f,
                            const float* __restrict__ wout_f,
                            bf16x8* __restrict__ wihPk, bf16x8* __restrict__ whhPk,
                            bf16x8* __restrict__ wopPk) {
  int c = blockIdx.x * 256 + threadIdx.x;
  int lane = c & 63, l15 = lane & 15, lk = (lane >> 4) & 3;
  if (c < 196608) {
    int cid = (c < 98304) ? c : c - 98304;
    const float* src = (c < 98304) ? wih_f : whh_f;
    bf16x8* dst = (c < 98304) ? wihPk : whhPk;
    int kk = (cid >> 6) & 15;
    int nt = cid >> 10;
    const float* p = src + (size_t)(nt * 16 + l15) * 512 + kk * 32 + lk * 8;
    bf16x8 o;
    #pragma unroll
    for (int i = 0; i < 8; ++i) o[i] = (bf16_t)p[i];
    dst[cid] = o;
  } else if (c < 197632) {
    int cid = c - 196608;          // vocab tile: 16 kk * 64 lane
    int kk = cid >> 6;
    bf16x8 o;
    if (l15 < 10) {
      const float* p = wout_f + (size_t)l15 * 512 + kk * 32 + lk * 8;
      #pragma unroll
      for (int i = 0; i < 8; ++i) o[i] = (bf16_t)p[i];
    } else {
      #pragma unroll
      for (int i = 0; i < 8; ++i) o[i] = (bf16_t)0.0f;
    }
    wopPk[cid] = o;
  }
}

__global__ __launch_bounds__(THREADS, 1) void gru_kernel(
    const float* __restrict__ x, const float* __restrict__ b_ih,
    const float* __restrict__ b_hh, const float* __restrict__ b_out,
    const bf16x8* __restrict__ wih, const bf16x8* __restrict__ whh,
    const bf16x8* __restrict__ wop,
    bf16x4* __restrict__ gi, bf16x4* __restrict__ hst, float* __restrict__ out) {
  // h tile: 128 rows x 512 bf16 (row = 1024B); logical col-byte L of row r at
  // physical L ^ ((r&7)<<4). Single buffer; h_new staged via hst (global).
  __shared__ __align__(16) char hlds[BM * 1024];

  const int tid   = (int)threadIdx.x;
  const int lane  = tid & 63;
  const int wq    = tid >> 6;      // 0..7: wave owns jtiles [wq*4, wq*4+4)
  const int l15   = lane & 15;
  const int lk    = lane >> 4;
  const int brow0 = (int)blockIdx.x * BM;
  const int swz   = (l15 & 7) << 4;
  const int kbase = (lk * 16) ^ swz;        // b128 read col base (XOR with kk*64)
  const int cbase = (lk * 8) ^ swz;         // b64 cell col base (XOR with jt*32)

  // ---------------- phase 0: x -> bf16 -> hlds (h0 = x) ----------------
  #pragma unroll
  for (int it = 0; it < 32; ++it) {
    int f4  = it * THREADS + tid;
    int row = f4 >> 7, c4 = f4 & 127;
    float4 v = ((const float4*)(x + (size_t)(brow0 + row) * 512))[c4];
    bf16x4 h4 = { (bf16_t)v.x, (bf16_t)v.y, (bf16_t)v.z, (bf16_t)v.w };
    *(bf16x4*)(&hlds[row * 1024 + ((c4 * 8) ^ ((row & 7) << 4))]) = h4;
  }
  __syncthreads();

  const size_t gibase = (size_t)blockIdx.x * 49152;  // bf16x4 chunks per block
  // gi chunk: ((jt*3 + g)*8 + bt)*64 + lane,  jt = wq*4 + p, bt 0..7
  const size_t hstbase = (size_t)blockIdx.x * 16384; // 256 chunks * 64
  // hst chunk: (jt*8 + bt)*64 + lane

  // ---------------- gi phase: gi = x @ w_ih^T + biases ----------------
  #pragma unroll
  for (int p = 0; p < 4; ++p) {
    const int jt = wq * 4 + p;
    f32x4 acc[3][8];
    #pragma unroll
    for (int g = 0; g < 3; ++g)
      #pragma unroll
      for (int bt = 0; bt < 8; ++bt) acc[g][bt] = (f32x4){0.f, 0.f, 0.f, 0.f};

    #pragma unroll 2
    for (int kk = 0; kk < 16; ++kk) {
      bf16x8 wfR = wih[((0 * 32 + jt) * 16 + kk) * 64 + lane];
      bf16x8 wfZ = wih[((1 * 32 + jt) * 16 + kk) * 64 + lane];
      bf16x8 wfN = wih[((2 * 32 + jt) * 16 + kk) * 64 + lane];
      #pragma unroll
      for (int q = 0; q < 2; ++q) {
        bf16x8 hf[4];
        #pragma unroll
        for (int b4 = 0; b4 < 4; ++b4)
          hf[b4] = *(const bf16x8*)(&hlds[((q * 4 + b4) * 16 + l15) * 1024 +
                                          ((kk * 64) ^ kbase)]);
        #pragma unroll
        for (int b4 = 0; b4 < 4; ++b4) {
          acc[0][q * 4 + b4] = __builtin_amdgcn_mfma_f32_16x16x32_bf16(wfR, hf[b4], acc[0][q * 4 + b4], 0, 0, 0);
          acc[1][q * 4 + b4] = __builtin_amdgcn_mfma_f32_16x16x32_bf16(wfZ, hf[b4], acc[1][q * 4 + b4], 0, 0, 0);
          acc[2][q * 4 + b4] = __builtin_amdgcn_mfma_f32_16x16x32_bf16(wfN, hf[b4], acc[2][q * 4 + b4], 0, 0, 0);
        }
      }
    }
    {
      int j = jt * 16 + lk * 4;
      f32x4 b0 = *(const f32x4*)(b_ih + j) + *(const f32x4*)(b_hh + j);
      f32x4 b1 = *(const f32x4*)(b_ih + 512 + j) + *(const f32x4*)(b_hh + 512 + j);
      f32x4 b2 = *(const f32x4*)(b_ih + 1024 + j);   // b_hh_n stays separate (x r)
      #pragma unroll
      for (int bt = 0; bt < 8; ++bt) {
        int cb = (jt * 3) * 8 + bt;
        gi[gibase + ((size_t)(cb + 0) << 6) + lane]  = pk4(acc[0][bt] + b0);
        gi[gibase + ((size_t)(cb + 8) << 6) + lane]  = pk4(acc[1][bt] + b1);
        gi[gibase + ((size_t)(cb + 16) << 6) + lane] = pk4(acc[2][bt] + b2);
      }
    }
  }
  // (no barrier: hlds unchanged; gi is same-lane RAW, HW-ordered)

  // ---------------- 6 recurrent steps (2 barriers each) ----------------
  for (int t = 0; t < NSTEP; ++t) {
    #pragma unroll
    for (int p = 0; p < 4; ++p) {
      const int jt = wq * 4 + p;
      const int cb = (jt * 3) * 8;

      f32x4 acc[3][8];
      #pragma unroll
      for (int g = 0; g < 3; ++g)
        #pragma unroll
        for (int bt = 0; bt < 8; ++bt) acc[g][bt] = (f32x4){0.f, 0.f, 0.f, 0.f};

      #pragma unroll 2
      for (int kk = 0; kk < 16; ++kk) {
        bf16x8 wfR = whh[((0 * 32 + jt) * 16 + kk) * 64 + lane];
        bf16x8 wfZ = whh[((1 * 32 + jt) * 16 + kk) * 64 + lane];
        bf16x8 wfN = whh[((2 * 32 + jt) * 16 + kk) * 64 + lane];
        #pragma unroll
        for (int q = 0; q < 2; ++q) {
          bf16x8 hf[4];
          #pragma unroll
          for (int b4 = 0; b4 < 4; ++b4)
            hf[b4] = *(const bf16x8*)(&hlds[((q * 4 + b4) * 16 + l15) * 1024 +
                                            ((kk * 64) ^ kbase)]);
          #pragma unroll
          for (int b4 = 0; b4 < 4; ++b4) {
            acc[0][q * 4 + b4] = __builtin_amdgcn_mfma_f32_16x16x32_bf16(wfR, hf[b4], acc[0][q * 4 + b4], 0, 0, 0);
            acc[1][q * 4 + b4] = __builtin_amdgcn_mfma_f32_16x16x32_bf16(wfZ, hf[b4], acc[1][q * 4 + b4], 0, 0, 0);
            acc[2][q * 4 + b4] = __builtin_amdgcn_mfma_f32_16x16x32_bf16(wfN, hf[b4], acc[2][q * 4 + b4], 0, 0, 0);
          }
        }
      }
      // GRU cell epilogue: per-bt direct gi loads (R6 pattern, no reg arrays);
      // h_new streamed to hst (coalesced, frees regs immediately).
      {
        int j = jt * 16 + lk * 4;
        f32x4 bn4 = *(const f32x4*)(b_hh + 1024 + j);
        #pragma unroll
        for (int bt = 0; bt < 8; ++bt) {
          bf16x4 grp = gi[gibase + ((size_t)(cb + 0 + bt) << 6) + lane];
          bf16x4 gzp = gi[gibase + ((size_t)(cb + 8 + bt) << 6) + lane];
          bf16x4 gnp = gi[gibase + ((size_t)(cb + 16 + bt) << 6) + lane];
          bf16x4 ho  = *(const bf16x4*)(&hlds[(bt * 16 + l15) * 1024 +
                                              ((jt * 32) ^ cbase)]);
          f32x4 gr = up4(grp), gz = up4(gzp), gn = up4(gnp), hov = up4(ho);
          f32x4 hv;
          #pragma unroll
          for (int r = 0; r < 4; ++r) {
            float rv = sigm(gr[r] + acc[0][bt][r]);
            float zv = sigm(gz[r] + acc[1][bt][r]);
            float nv = tanhf_(gn[r] + rv * (acc[2][bt][r] + bn4[r]));
            hv[r] = (1.0f - zv) * nv + zv * hov[r];
          }
          hst[hstbase + ((size_t)((jt << 3) + bt) << 6) + lane] = pk4(hv);
        }
      }
    }
    __syncthreads();   // all h_t reads done; hst stores drained (vmcnt)

    // copy-back: reload own chunks from hst (L2-hit, coalesced), ds_write hlds
    #pragma unroll
    for (int p = 0; p < 4; ++p) {
      const int jt = wq * 4 + p;
      #pragma unroll
      for (int bt = 0; bt < 8; ++bt) {
        bf16x4 v = hst[hstbase + ((size_t)((jt << 3) + bt) << 6) + lane];
        *(bf16x4*)(&hlds[(bt * 16 + l15) * 1024 + ((jt * 32) ^ cbase)]) = v;
      }
    }
    __syncthreads();   // h_{t+1} visible

    // logits_t = h_{t+1} @ w_out^T + b_out ; wave wq owns btile wq
    {
      f32x4 lacc = (f32x4){0.f, 0.f, 0.f, 0.f};
      #pragma unroll 2
      for (int kk = 0; kk < 16; ++kk) {
        bf16x8 hf = *(const bf16x8*)(&hlds[(wq * 16 + l15) * 1024 + ((kk * 64) ^ kbase)]);
        bf16x8 wf = wop[kk * 64 + lane];
        lacc = __builtin_amdgcn_mfma_f32_16x16x32_bf16(wf, hf, lacc, 0, 0, 0);
      }
      size_t ob = (size_t)(brow0 + wq * 16 + l15) * 60 + t * 10 + lk * 4;
      if (lk < 2) {
        f32x2 a = { lacc[0] + b_out[lk * 4 + 0], lacc[1] + b_out[lk * 4 + 1] };
        f32x2 b = { lacc[2] + b_out[lk * 4 + 2], lacc[3] + b_out[lk * 4 + 3] };
        *(f32x2*)(out + ob) = a;
        *(f32x2*)(out + ob + 2) = b;
      } else if (lk == 2) {
        f32x2 a = { lacc[0] + b_out[8], lacc[1] + b_out[9] };
        *(f32x2*)(out + ob) = a;
      }
    }
  }
}

extern "C" void kernel_launch(void* const* d_in, const int* in_sizes, int n_in,
                              void* d_out, int out_size, void* d_ws, size_t ws_size,
                              hipStream_t stream) {
  const float* x     = (const float*)d_in[0];
  const float* wih_f = (const float*)d_in[1];
  const float* whh_f = (const float*)d_in[2];
  const float* b_ih  = (const float*)d_in[3];
  const float* b_hh  = (const float*)d_in[4];
  const float* wout  = (const float*)d_in[5];
  const float* b_out = (const float*)d_in[6];

  char* ws = (char*)d_ws;
  bf16x8* wihPk = (bf16x8*)(ws + WIH_OFF);
  bf16x8* whhPk = (bf16x8*)(ws + WHH_OFF);
  bf16x8* wopPk = (bf16x8*)(ws + WOP_OFF);
  bf16x4* gi    = (bf16x4*)(ws + GI_OFF);
  bf16x4* hst   = (bf16x4*)(ws + HST_OFF);

  prep_kernel<<<772, 256, 0, stream>>>(wih_f, whh_f, wout, wihPk, whhPk, wopPk);
  gru_kernel<<<NBLK, THREADS, 0, stream>>>(x, b_ih, b_hh, b_out,
                                           wihPk, whhPk, wopPk, gi, hst, (float*)d_out);
}

// Round 15
// 642.689 us; speedup vs baseline: 2.4556x; 1.0122x over previous
//
#include <hip/hip_runtime.h>
#include <hip/hip_bf16.h>
#include <stdint.h>

// GRU sequence decoder, fused. B=32768, H=L=512, VOCAB=10, SEQ=6.
// R15 = R14 (BM=128, halves weight L2 stream) + sched_barrier(0) fences to
// cap the epilogue's in-flight register window (R14 evidence: ~58MB residual
// spill from the compiler hoisting 24 gi loads + 8 ho over the 8-bt epilogue
// and overlapping the next pass's k-loop). Fences: one before the epilogue,
// one between the two 4-bt epilogue halves -> in-flight ~32 regs.
// Register model (R2/R11-R14): per-wave 256 unified; acc in AGPR cheap
// (acc[3][8]=96 AGPR); arch VGPR must stay <=128; k-loop quad-split keeps
// ~60 arch in flight; NO gi/gpre register arrays.
// Structure: 8 waves, wave owns jtiles [wq*4,wq*4+4) x all 8 btiles; h single
// buffer in LDS (128KB, XOR swizzle); h_new via hst global round-trip,
// 2 barriers/step; gi in ws per-lane frag order (same-lane RAW); weights
// pre-packed frag order (L2-resident); logits: wave wq owns btile wq.
// __launch_bounds__(512,1), NBLK=256.

typedef __bf16 bf16_t;
typedef bf16_t bf16x8 __attribute__((ext_vector_type(8)));
typedef bf16_t bf16x4 __attribute__((ext_vector_type(4)));
typedef float  f32x4  __attribute__((ext_vector_type(4)));
typedef float  f32x2  __attribute__((ext_vector_type(2)));

#define THREADS 512
#define BM      128
#define NBLK    256
#define NSTEP   6

// ws layout (bytes)
#define WIH_OFF 0u            // 96 nt * 16 kk * 64 lane * 16B = 1572864
#define WHH_OFF 1572864u
#define WOP_OFF 3145728u      // 16 kk * 64 lane * 16B = 16384
#define GI_OFF  4194304u      // 256 blk * 49152 chunks * 8B = 100663296
#define HST_OFF 104857600u    // 256 blk * 256 chunks * 512B = 33554432

static __device__ __forceinline__ float sigm(float v) { return 1.0f / (1.0f + __expf(-v)); }
static __device__ __forceinline__ float tanhf_(float v) {
  v = fminf(fmaxf(v, -12.0f), 12.0f);
  float e = __expf(2.0f * v);
  return 1.0f - 2.0f / (e + 1.0f);
}
static __device__ __forceinline__ f32x4 up4(bf16x4 v) {
  f32x4 o; o[0] = (float)v[0]; o[1] = (float)v[1]; o[2] = (float)v[2]; o[3] = (float)v[3];
  return o;
}
static __device__ __forceinline__ bf16x4 pk4(f32x4 v) {
  bf16x4 o; o[0] = (bf16_t)v[0]; o[1] = (bf16_t)v[1]; o[2] = (bf16_t)v[2]; o[3] = (bf16_t)v[3];
  return o;
}

// Pack weights into MFMA A-frag order:
//   chunk[(nt*16 + kk)*64 + lane] = w[nt*16 + (lane&15)][kk*32 + (lane>>4)*8 .. +8]
__global__ void prep_kernel(const float* __restrict__ wih_f, const float* __restrict__ whh_f,
                            const float* __restrict__ wout_f,
                            bf16x8* __restrict__ wihPk, bf16x8* __restrict__ whhPk,
                            bf16x8* __restrict__ wopPk) {
  int c = blockIdx.x * 256 + threadIdx.x;
  int lane = c & 63, l15 = lane & 15, lk = (lane >> 4) & 3;
  if (c < 196608) {
    int cid = (c < 98304) ? c : c - 98304;
    const float* src = (c < 98304) ? wih_f : whh_f;
    bf16x8* dst = (c < 98304) ? wihPk : whhPk;
    int kk = (cid >> 6) & 15;
    int nt = cid >> 10;
    const float* p = src + (size_t)(nt * 16 + l15) * 512 + kk * 32 + lk * 8;
    bf16x8 o;
    #pragma unroll
    for (int i = 0; i < 8; ++i) o[i] = (bf16_t)p[i];
    dst[cid] = o;
  } else if (c < 197632) {
    int cid = c - 196608;          // vocab tile: 16 kk * 64 lane
    int kk = cid >> 6;
    bf16x8 o;
    if (l15 < 10) {
      const float* p = wout_f + (size_t)l15 * 512 + kk * 32 + lk * 8;
      #pragma unroll
      for (int i = 0; i < 8; ++i) o[i] = (bf16_t)p[i];
    } else {
      #pragma unroll
      for (int i = 0; i < 8; ++i) o[i] = (bf16_t)0.0f;
    }
    wopPk[cid] = o;
  }
}

__global__ __launch_bounds__(THREADS, 1) void gru_kernel(
    const float* __restrict__ x, const float* __restrict__ b_ih,
    const float* __restrict__ b_hh, const float* __restrict__ b_out,
    const bf16x8* __restrict__ wih, const bf16x8* __restrict__ whh,
    const bf16x8* __restrict__ wop,
    bf16x4* __restrict__ gi, bf16x4* __restrict__ hst, float* __restrict__ out) {
  // h tile: 128 rows x 512 bf16 (row = 1024B); logical col-byte L of row r at
  // physical L ^ ((r&7)<<4). Single buffer; h_new staged via hst (global).
  __shared__ __align__(16) char hlds[BM * 1024];

  const int tid   = (int)threadIdx.x;
  const int lane  = tid & 63;
  const int wq    = tid >> 6;      // 0..7: wave owns jtiles [wq*4, wq*4+4)
  const int l15   = lane & 15;
  const int lk    = lane >> 4;
  const int brow0 = (int)blockIdx.x * BM;
  const int swz   = (l15 & 7) << 4;
  const int kbase = (lk * 16) ^ swz;        // b128 read col base (XOR with kk*64)
  const int cbase = (lk * 8) ^ swz;         // b64 cell col base (XOR with jt*32)

  // ---------------- phase 0: x -> bf16 -> hlds (h0 = x) ----------------
  #pragma unroll
  for (int it = 0; it < 32; ++it) {
    int f4  = it * THREADS + tid;
    int row = f4 >> 7, c4 = f4 & 127;
    float4 v = ((const float4*)(x + (size_t)(brow0 + row) * 512))[c4];
    bf16x4 h4 = { (bf16_t)v.x, (bf16_t)v.y, (bf16_t)v.z, (bf16_t)v.w };
    *(bf16x4*)(&hlds[row * 1024 + ((c4 * 8) ^ ((row & 7) << 4))]) = h4;
  }
  __syncthreads();

  const size_t gibase = (size_t)blockIdx.x * 49152;  // bf16x4 chunks per block
  // gi chunk: ((jt*3 + g)*8 + bt)*64 + lane,  jt = wq*4 + p, bt 0..7
  const size_t hstbase = (size_t)blockIdx.x * 16384; // 256 chunks * 64
  // hst chunk: (jt*8 + bt)*64 + lane

  // ---------------- gi phase: gi = x @ w_ih^T + biases ----------------
  #pragma unroll
  for (int p = 0; p < 4; ++p) {
    const int jt = wq * 4 + p;
    f32x4 acc[3][8];
    #pragma unroll
    for (int g = 0; g < 3; ++g)
      #pragma unroll
      for (int bt = 0; bt < 8; ++bt) acc[g][bt] = (f32x4){0.f, 0.f, 0.f, 0.f};

    #pragma unroll 2
    for (int kk = 0; kk < 16; ++kk) {
      bf16x8 wfR = wih[((0 * 32 + jt) * 16 + kk) * 64 + lane];
      bf16x8 wfZ = wih[((1 * 32 + jt) * 16 + kk) * 64 + lane];
      bf16x8 wfN = wih[((2 * 32 + jt) * 16 + kk) * 64 + lane];
      #pragma unroll
      for (int q = 0; q < 2; ++q) {
        bf16x8 hf[4];
        #pragma unroll
        for (int b4 = 0; b4 < 4; ++b4)
          hf[b4] = *(const bf16x8*)(&hlds[((q * 4 + b4) * 16 + l15) * 1024 +
                                          ((kk * 64) ^ kbase)]);
        #pragma unroll
        for (int b4 = 0; b4 < 4; ++b4) {
          acc[0][q * 4 + b4] = __builtin_amdgcn_mfma_f32_16x16x32_bf16(wfR, hf[b4], acc[0][q * 4 + b4], 0, 0, 0);
          acc[1][q * 4 + b4] = __builtin_amdgcn_mfma_f32_16x16x32_bf16(wfZ, hf[b4], acc[1][q * 4 + b4], 0, 0, 0);
          acc[2][q * 4 + b4] = __builtin_amdgcn_mfma_f32_16x16x32_bf16(wfN, hf[b4], acc[2][q * 4 + b4], 0, 0, 0);
        }
      }
    }
    __builtin_amdgcn_sched_barrier(0);   // keep epilogue out of k-loop window
    {
      int j = jt * 16 + lk * 4;
      f32x4 b0 = *(const f32x4*)(b_ih + j) + *(const f32x4*)(b_hh + j);
      f32x4 b1 = *(const f32x4*)(b_ih + 512 + j) + *(const f32x4*)(b_hh + 512 + j);
      f32x4 b2 = *(const f32x4*)(b_ih + 1024 + j);   // b_hh_n stays separate (x r)
      #pragma unroll
      for (int q = 0; q < 2; ++q) {
        #pragma unroll
        for (int b4 = 0; b4 < 4; ++b4) {
          int bt = q * 4 + b4;
          int cb = (jt * 3) * 8 + bt;
          gi[gibase + ((size_t)(cb + 0) << 6) + lane]  = pk4(acc[0][bt] + b0);
          gi[gibase + ((size_t)(cb + 8) << 6) + lane]  = pk4(acc[1][bt] + b1);
          gi[gibase + ((size_t)(cb + 16) << 6) + lane] = pk4(acc[2][bt] + b2);
        }
        __builtin_amdgcn_sched_barrier(0);
      }
    }
  }
  // (no barrier: hlds unchanged; gi is same-lane RAW, HW-ordered)

  // ---------------- 6 recurrent steps (2 barriers each) ----------------
  for (int t = 0; t < NSTEP; ++t) {
    #pragma unroll
    for (int p = 0; p < 4; ++p) {
      const int jt = wq * 4 + p;
      const int cb = (jt * 3) * 8;

      f32x4 acc[3][8];
      #pragma unroll
      for (int g = 0; g < 3; ++g)
        #pragma unroll
        for (int bt = 0; bt < 8; ++bt) acc[g][bt] = (f32x4){0.f, 0.f, 0.f, 0.f};

      #pragma unroll 2
      for (int kk = 0; kk < 16; ++kk) {
        bf16x8 wfR = whh[((0 * 32 + jt) * 16 + kk) * 64 + lane];
        bf16x8 wfZ = whh[((1 * 32 + jt) * 16 + kk) * 64 + lane];
        bf16x8 wfN = whh[((2 * 32 + jt) * 16 + kk) * 64 + lane];
        #pragma unroll
        for (int q = 0; q < 2; ++q) {
          bf16x8 hf[4];
          #pragma unroll
          for (int b4 = 0; b4 < 4; ++b4)
            hf[b4] = *(const bf16x8*)(&hlds[((q * 4 + b4) * 16 + l15) * 1024 +
                                            ((kk * 64) ^ kbase)]);
          #pragma unroll
          for (int b4 = 0; b4 < 4; ++b4) {
            acc[0][q * 4 + b4] = __builtin_amdgcn_mfma_f32_16x16x32_bf16(wfR, hf[b4], acc[0][q * 4 + b4], 0, 0, 0);
            acc[1][q * 4 + b4] = __builtin_amdgcn_mfma_f32_16x16x32_bf16(wfZ, hf[b4], acc[1][q * 4 + b4], 0, 0, 0);
            acc[2][q * 4 + b4] = __builtin_amdgcn_mfma_f32_16x16x32_bf16(wfN, hf[b4], acc[2][q * 4 + b4], 0, 0, 0);
          }
        }
      }
      __builtin_amdgcn_sched_barrier(0);   // fence: epilogue loads stay here
      // GRU cell epilogue in two fenced 4-bt halves (caps in-flight ~32 regs)
      {
        int j = jt * 16 + lk * 4;
        f32x4 bn4 = *(const f32x4*)(b_hh + 1024 + j);
        #pragma unroll
        for (int q = 0; q < 2; ++q) {
          #pragma unroll
          for (int b4 = 0; b4 < 4; ++b4) {
            int bt = q * 4 + b4;
            bf16x4 grp = gi[gibase + ((size_t)(cb + 0 + bt) << 6) + lane];
            bf16x4 gzp = gi[gibase + ((size_t)(cb + 8 + bt) << 6) + lane];
            bf16x4 gnp = gi[gibase + ((size_t)(cb + 16 + bt) << 6) + lane];
            bf16x4 ho  = *(const bf16x4*)(&hlds[(bt * 16 + l15) * 1024 +
                                                ((jt * 32) ^ cbase)]);
            f32x4 gr = up4(grp), gz = up4(gzp), gn = up4(gnp), hov = up4(ho);
            f32x4 hv;
            #pragma unroll
            for (int r = 0; r < 4; ++r) {
              float rv = sigm(gr[r] + acc[0][bt][r]);
              float zv = sigm(gz[r] + acc[1][bt][r]);
              float nv = tanhf_(gn[r] + rv * (acc[2][bt][r] + bn4[r]));
              hv[r] = (1.0f - zv) * nv + zv * hov[r];
            }
            hst[hstbase + ((size_t)((jt << 3) + bt) << 6) + lane] = pk4(hv);
          }
          __builtin_amdgcn_sched_barrier(0);
        }
      }
    }
    __syncthreads();   // all h_t reads done; hst stores drained (vmcnt)

    // copy-back: reload own chunks from hst (L2-hit, coalesced), ds_write hlds
    #pragma unroll
    for (int p = 0; p < 4; ++p) {
      const int jt = wq * 4 + p;
      #pragma unroll
      for (int bt = 0; bt < 8; ++bt) {
        bf16x4 v = hst[hstbase + ((size_t)((jt << 3) + bt) << 6) + lane];
        *(bf16x4*)(&hlds[(bt * 16 + l15) * 1024 + ((jt * 32) ^ cbase)]) = v;
      }
    }
    __syncthreads();   // h_{t+1} visible

    // logits_t = h_{t+1} @ w_out^T + b_out ; wave wq owns btile wq
    {
      f32x4 lacc = (f32x4){0.f, 0.f, 0.f, 0.f};
      #pragma unroll 2
      for (int kk = 0; kk < 16; ++kk) {
        bf16x8 hf = *(const bf16x8*)(&hlds[(wq * 16 + l15) * 1024 + ((kk * 64) ^ kbase)]);
        bf16x8 wf = wop[kk * 64 + lane];
        lacc = __builtin_amdgcn_mfma_f32_16x16x32_bf16(wf, hf, lacc, 0, 0, 0);
      }
      size_t ob = (size_t)(brow0 + wq * 16 + l15) * 60 + t * 10 + lk * 4;
      if (lk < 2) {
        f32x2 a = { lacc[0] + b_out[lk * 4 + 0], lacc[1] + b_out[lk * 4 + 1] };
        f32x2 b = { lacc[2] + b_out[lk * 4 + 2], lacc[3] + b_out[lk * 4 + 3] };
        *(f32x2*)(out + ob) = a;
        *(f32x2*)(out + ob + 2) = b;
      } else if (lk == 2) {
        f32x2 a = { lacc[0] + b_out[8], lacc[1] + b_out[9] };
        *(f32x2*)(out + ob) = a;
      }
    }
  }
}

extern "C" void kernel_launch(void* const* d_in, const int* in_sizes, int n_in,
                              void* d_out, int out_size, void* d_ws, size_t ws_size,
                              hipStream_t stream) {
  const float* x     = (const float*)d_in[0];
  const float* wih_f = (const float*)d_in[1];
  const float* whh_f = (const float*)d_in[2];
  const float* b_ih  = (const float*)d_in[3];
  const float* b_hh  = (const float*)d_in[4];
  const float* wout  = (const float*)d_in[5];
  const float* b_out = (const float*)d_in[6];

  char* ws = (char*)d_ws;
  bf16x8* wihPk = (bf16x8*)(ws + WIH_OFF);
  bf16x8* whhPk = (bf16x8*)(ws + WHH_OFF);
  bf16x8* wopPk = (bf16x8*)(ws + WOP_OFF);
  bf16x4* gi    = (bf16x4*)(ws + GI_OFF);
  bf16x4* hst   = (bf16x4*)(ws + HST_OFF);

  prep_kernel<<<772, 256, 0, stream>>>(wih_f, whh_f, wout, wihPk, whhPk, wopPk);
  gru_kernel<<<NBLK, THREADS, 0, stream>>>(x, b_ih, b_hh, b_out,
                                           wihPk, whhPk, wopPk, gi, hst, (float*)d_out);
}